// Round 6
// baseline (1268.918 us; speedup 1.0000x reference)
//
#include <hip/hip_runtime.h>

typedef unsigned short u16;
typedef unsigned int u32;
using f32x4 = __attribute__((ext_vector_type(4))) float;
using bf16x8 = __attribute__((ext_vector_type(8))) short;

#define EPSF 1e-8f

constexpr int C1 = 768;
constexpr int HW = 9216;        // 96*96
constexpr int CJ = 2304;        // 3*768 joint channels
constexpr int BM = 128, BN = 128, BK = 32;
constexpr int NT = CJ / BK;     // 72 k-tiles (even)
constexpr int NS = 24;          // N splits
constexpr int TPS = (HW / BN) / NS; // 3 col-tiles per split

__device__ __forceinline__ u16 f2bf(float f) {
    u32 u = __float_as_uint(f);
    u += 0x7FFFu + ((u >> 16) & 1u);   // RNE
    return (u16)(u >> 16);
}
__device__ __forceinline__ float bf2f(u16 h) {
    return __uint_as_float(((u32)h) << 16);
}

// async global->LDS DMA, 16B per lane. LDS dest = wave-uniform base + lane*16.
__device__ __forceinline__ void gl_lds16(const u16* g, u16* l) {
    __builtin_amdgcn_global_load_lds(
        (const __attribute__((address_space(1))) void*)g,
        (__attribute__((address_space(3))) void*)l, 16, 0, 0);
}

// ---------------- transpose + fp32->bf16: out[j][c] = in[c][j] ----------------
__global__ void k_transpose(const float* __restrict__ s0, const float* __restrict__ s1,
                            const float* __restrict__ s2, u16* __restrict__ dst) {
    __shared__ float tile[32][33];
    const int j0 = blockIdx.x * 32;
    const int c0 = blockIdx.y * 32;
    const int tx = threadIdx.x, ty = threadIdx.y;
    const int seg = (c0 >= 1536) ? 2 : (c0 >= 768) ? 1 : 0;   // 768 not pow2: no & trick
    const float* src = (seg == 0) ? s0 : (seg == 1) ? s1 : s2;
    const int cb = c0 - seg * 768;
#pragma unroll
    for (int r = 0; r < 4; ++r) {
        int cc = ty + r * 8;
        tile[cc][tx] = src[(size_t)(cb + cc) * HW + j0 + tx];
    }
    __syncthreads();
#pragma unroll
    for (int r = 0; r < 4; ++r) {
        int jj = ty + r * 8;
        dst[(size_t)(j0 + jj) * CJ + c0 + tx] = f2bf(tile[tx][jj]);
    }
}

// ---------------- per-column squared sums + 1/(sqrt(s)+eps) for all 6 mats ----------------
__global__ void k_colsq(const float* __restrict__ p0, const float* __restrict__ p1,
                        const float* __restrict__ p2, const float* __restrict__ p3,
                        const float* __restrict__ p4, const float* __restrict__ p5,
                        float* __restrict__ sq, float* __restrict__ inv) {
    const float* src;
    switch (blockIdx.y) {
        case 0: src = p0; break; case 1: src = p1; break; case 2: src = p2; break;
        case 3: src = p3; break; case 4: src = p4; break; default: src = p5; break;
    }
    const int j = blockIdx.x * 256 + threadIdx.x;
    float s = 0.f;
#pragma unroll 8
    for (int c = 0; c < C1; ++c) {
        float v = src[(size_t)c * HW + j];
        s = fmaf(v, v, s);
    }
    sq[blockIdx.y * HW + j] = s;
    inv[blockIdx.y * HW + j] = 1.0f / (sqrtf(s) + EPSF);
}

// ---------------- joint style norm: 1/(sqrt(s1+s3+s5+EPS)+EPS) ----------------
__global__ void k_joint(const float* __restrict__ sq, float* __restrict__ invbnj) {
    const int j = blockIdx.x * 256 + threadIdx.x;
    float s = sq[1 * HW + j] + sq[3 * HW + j] + sq[5 * HW + j];
    invbnj[j] = 1.0f / (sqrtf(s + EPSF) + EPSF);
}

// ---------------- fused GEMM (G = CT^T*ST via bf16 MFMA) + per-row arg best/worst ----------------
// Round 5: gl_lds DMA staging + LDS double-buffer, STAGE issued BEFORE compute
// (T3 minimum 2-phase: loads in flight across the MFMA phase), one barrier/k-step.
// XCD-bijective row-tile swizzle (72 = 8*9) pins A rows to one XCD's L2 across splits.
__global__ __launch_bounds__(256) void k_gemm_arg(
    const u16* __restrict__ CT, const u16* __restrict__ ST,
    const float* __restrict__ invbn,
    float* __restrict__ bestv, int* __restrict__ besti,
    float* __restrict__ worstv, int* __restrict__ worsti) {
    __shared__ u16 ldsA0[BM * BK], ldsA1[BM * BK];
    __shared__ u16 ldsB0[BN * BK], ldsB1[BN * BK];
    __shared__ float s_bv[2][BM]; __shared__ int s_bi[2][BM];
    __shared__ float s_wv[2][BM]; __shared__ int s_wi[2][BM];

    const int tid = threadIdx.x;
    const int l = tid & 63;
    const int w = tid >> 6;
    const int wr = w >> 1, wc = w & 1;
    // bijective XCD swizzle: linear dispatch id = x + 72*y, 72%8==0 -> XCD = x%8.
    // Row-tile = (x%8)*9 + x/8: each XCD keeps 9 fixed A row-tiles hot in its L2.
    const int bx = (blockIdx.x & 7) * 9 + (blockIdx.x >> 3);
    const int sp = blockIdx.y;
    const int rowbase = bx * BM;

    if (tid < BM) {
        s_bv[0][tid] = -3.4e38f; s_bv[1][tid] = -3.4e38f;
        s_wv[0][tid] =  3.4e38f; s_wv[1][tid] =  3.4e38f;
        s_bi[0][tid] = 0x7fffffff; s_bi[1][tid] = 0x7fffffff;
        s_wi[0][tid] = 0x7fffffff; s_wi[1][tid] = 0x7fffffff;
    }

    // DMA staging geometry: wave w covers tile rows [32w, 32w+32) as two
    // 16-row x 64B chunks (1 KiB = one gl_lds16 each). Lane l -> row +(l>>2),
    // slot l&3; source slot pre-swizzled with the read-side XOR involution.
    const int sr = l >> 2;
    const int ss = l & 3;
    const int rA0 = w * 32 + sr;
    const int rA1 = rA0 + 16;
    const int gs0 = ss ^ ((rA0 >> 1) & 3);
    const int gs1 = ss ^ ((rA1 >> 1) & 3);
    const size_t aofs0 = (size_t)(rowbase + rA0) * CJ + gs0 * 8;
    const size_t aofs1 = (size_t)(rowbase + rA1) * CJ + gs1 * 8;
    const int wb = __builtin_amdgcn_readfirstlane(w * 32 * BK);  // SGPR-pinned LDS base
    u16* A0c0 = ldsA0 + wb; u16* A0c1 = ldsA0 + wb + 16 * BK;
    u16* A1c0 = ldsA1 + wb; u16* A1c1 = ldsA1 + wb + 16 * BK;
    u16* B0c0 = ldsB0 + wb; u16* B0c1 = ldsB0 + wb + 16 * BK;
    u16* B1c0 = ldsB1 + wb; u16* B1c1 = ldsB1 + wb + 16 * BK;

    const int frow = l & 15;
    const int fk = l >> 4;
    const f32x4 fzero = {0.f, 0.f, 0.f, 0.f};

#pragma unroll 1
    for (int ct = 0; ct < TPS; ++ct) {
        const int colbase = (sp * TPS + ct) * BN;
        const size_t bofs0 = (size_t)(colbase + rA0) * CJ + gs0 * 8;
        const size_t bofs1 = (size_t)(colbase + rA1) * CJ + gs1 * 8;

        f32x4 acc[4][4];
#pragma unroll
        for (int m = 0; m < 4; ++m)
#pragma unroll
            for (int n = 0; n < 4; ++n) acc[m][n] = fzero;

        auto stage = [&](u16* dA0, u16* dA1, u16* dB0, u16* dB1, int kt) {
            const size_t ko = (size_t)kt * BK;
            gl_lds16(CT + aofs0 + ko, dA0);
            gl_lds16(CT + aofs1 + ko, dA1);
            gl_lds16(ST + bofs0 + ko, dB0);
            gl_lds16(ST + bofs1 + ko, dB1);
        };
        auto compute = [&](const u16* bA, const u16* bB) {
            bf16x8 af[4], bfr[4];
#pragma unroll
            for (int m = 0; m < 4; ++m) {
                int row = wr * 64 + m * 16 + frow;
                int slot = fk ^ ((row >> 1) & 3);
                af[m] = *(const bf16x8*)&bA[row * BK + slot * 8];
            }
#pragma unroll
            for (int n = 0; n < 4; ++n) {
                int col = wc * 64 + n * 16 + frow;
                int slot = fk ^ ((col >> 1) & 3);
                bfr[n] = *(const bf16x8*)&bB[col * BK + slot * 8];
            }
#pragma unroll
            for (int m = 0; m < 4; ++m)
#pragma unroll
                for (int n = 0; n < 4; ++n)
                    acc[m][n] = __builtin_amdgcn_mfma_f32_16x16x32_bf16(af[m], bfr[n], acc[m][n], 0, 0, 0);
        };

        stage(A0c0, A0c1, B0c0, B0c1, 0);
        __syncthreads();                       // buf0 ready
#pragma unroll 1
        for (int kt = 0; kt < NT; kt += 2) {
            stage(A1c0, A1c1, B1c0, B1c1, kt + 1);   // in flight during compute
            compute(ldsA0, ldsB0);
            __syncthreads();                   // drain: buf1 ready, buf0 reads done
            if (kt + 2 < NT) stage(A0c0, A0c1, B0c0, B0c1, kt + 2);
            compute(ldsA1, ldsB1);
            __syncthreads();                   // drain: buf0 ready, buf1 reads done
        }

        // epilogue: score = G * invbn[col]; per-row best/worst over this col-tile
        float ib[4];
#pragma unroll
        for (int n = 0; n < 4; ++n) ib[n] = invbn[colbase + wc * 64 + n * 16 + frow];

#pragma unroll
        for (int m = 0; m < 4; ++m) {
#pragma unroll
            for (int i = 0; i < 4; ++i) {
                float bv = -3.4e38f, wv = 3.4e38f; int bi = 0x7fffffff, wi = 0x7fffffff;
#pragma unroll
                for (int n = 0; n < 4; ++n) {
                    float sc = acc[m][n][i] * ib[n];
                    int ci = colbase + wc * 64 + n * 16 + frow;
                    if (sc > bv) { bv = sc; bi = ci; }
                    if (sc < wv) { wv = sc; wi = ci; }
                }
#pragma unroll
                for (int d = 1; d < 16; d <<= 1) {   // reduce the 16 lanes sharing these rows
                    float obv = __shfl_xor(bv, d); int obi = __shfl_xor(bi, d);
                    if (obv > bv || (obv == bv && obi < bi)) { bv = obv; bi = obi; }
                    float owv = __shfl_xor(wv, d); int owi = __shfl_xor(wi, d);
                    if (owv < wv || (owv == wv && owi < wi)) { wv = owv; wi = owi; }
                }
                if ((l & 15) == 0) {
                    int rl = wr * 64 + m * 16 + (l >> 4) * 4 + i;
                    if (bv > s_bv[wc][rl] || (bv == s_bv[wc][rl] && bi < s_bi[wc][rl])) { s_bv[wc][rl] = bv; s_bi[wc][rl] = bi; }
                    if (wv < s_wv[wc][rl] || (wv == s_wv[wc][rl] && wi < s_wi[wc][rl])) { s_wv[wc][rl] = wv; s_wi[wc][rl] = wi; }
                }
            }
        }
    }

    __syncthreads();
    if (tid < BM) {
        float bv = s_bv[0][tid]; int bi = s_bi[0][tid];
        if (s_bv[1][tid] > bv || (s_bv[1][tid] == bv && s_bi[1][tid] < bi)) { bv = s_bv[1][tid]; bi = s_bi[1][tid]; }
        float wv = s_wv[0][tid]; int wi = s_wi[0][tid];
        if (s_wv[1][tid] < wv || (s_wv[1][tid] == wv && s_wi[1][tid] < wi)) { wv = s_wv[1][tid]; wi = s_wi[1][tid]; }
        bestv [(size_t)sp * HW + rowbase + tid] = bv;
        besti [(size_t)sp * HW + rowbase + tid] = bi;
        worstv[(size_t)sp * HW + rowbase + tid] = wv;
        worsti[(size_t)sp * HW + rowbase + tid] = wi;
    }
}

// ---------------- final: reduce splits, gathered cosines, loss ----------------
__global__ void k_final(const u16* __restrict__ CT, const u16* __restrict__ ST,
                        const float* __restrict__ inv6,
                        const float* __restrict__ bestv, const int* __restrict__ besti,
                        const float* __restrict__ worstv, const int* __restrict__ worsti,
                        float* __restrict__ out) {
    const int w = threadIdx.x >> 6, l = threadIdx.x & 63;
    const int r = blockIdx.x * 4 + w;

    float bv = -3.4e38f, wv = 3.4e38f; int bi = 0x7fffffff, wi = 0x7fffffff;
    if (l < NS) {
        bv = bestv [(size_t)l * HW + r]; bi = besti [(size_t)l * HW + r];
        wv = worstv[(size_t)l * HW + r]; wi = worsti[(size_t)l * HW + r];
    }
#pragma unroll
    for (int d = 1; d < 64; d <<= 1) {
        float obv = __shfl_xor(bv, d); int obi = __shfl_xor(bi, d);
        if (obv > bv || (obv == bv && obi < bi)) { bv = obv; bi = obi; }
        float owv = __shfl_xor(wv, d); int owi = __shfl_xor(wi, d);
        if (owv < wv || (owv == wv && owi < wi)) { wv = owv; wi = owi; }
    }
    const int zb = bi, zw = wi;

    const u16* ar = CT + (size_t)r * CJ;
    const u16* bb = ST + (size_t)zb * CJ;
    const u16* bw = ST + (size_t)zw * CJ;
    float db[3] = {0.f, 0.f, 0.f}, dw[3] = {0.f, 0.f, 0.f};
#pragma unroll
    for (int it = 0; it < 9; ++it) {
        const int c = it * 256 + l * 4;
        uint2 va = *(const uint2*)(ar + c);
        uint2 vb = *(const uint2*)(bb + c);
        uint2 vw = *(const uint2*)(bw + c);
        const int seg = it / 3;  // 0: feats, 1: depth, 2: edge (768 = 3*256)
        float a0 = bf2f((u16)(va.x & 0xffff)), a1 = bf2f((u16)(va.x >> 16));
        float a2 = bf2f((u16)(va.y & 0xffff)), a3 = bf2f((u16)(va.y >> 16));
        float b0 = bf2f((u16)(vb.x & 0xffff)), b1 = bf2f((u16)(vb.x >> 16));
        float b2 = bf2f((u16)(vb.y & 0xffff)), b3 = bf2f((u16)(vb.y >> 16));
        float w0 = bf2f((u16)(vw.x & 0xffff)), w1 = bf2f((u16)(vw.x >> 16));
        float w2 = bf2f((u16)(vw.y & 0xffff)), w3 = bf2f((u16)(vw.y >> 16));
        db[seg] += a0 * b0 + a1 * b1 + a2 * b2 + a3 * b3;
        dw[seg] += a0 * w0 + a1 * w1 + a2 * w2 + a3 * w3;
    }
#pragma unroll
    for (int d = 1; d < 64; d <<= 1) {
#pragma unroll
        for (int s = 0; s < 3; ++s) {
            db[s] += __shfl_xor(db[s], d);
            dw[s] += __shfl_xor(dw[s], d);
        }
    }
    if (l == 0) {
        float c0 = db[0] * inv6[0 * HW + r] * inv6[1 * HW + zb];
        float c1 = db[1] * inv6[2 * HW + r] * inv6[3 * HW + zb];
        float c2 = db[2] * inv6[4 * HW + r] * inv6[5 * HW + zb];
        float d0 = dw[0] * inv6[0 * HW + r] * inv6[1 * HW + zw];
        float d1 = dw[1] * inv6[2 * HW + r] * inv6[3 * HW + zw];
        float d2 = dw[2] * inv6[4 * HW + r] * inv6[5 * HW + zw];
        float contrib = (6.0f - c0 - c1 - c2 + d0 + d1 + d2) * (1.0f / 9216.0f);
        atomicAdd(out, contrib);
    }
}

extern "C" void kernel_launch(void* const* d_in, const int* in_sizes, int n_in,
                              void* d_out, int out_size, void* d_ws, size_t ws_size,
                              hipStream_t stream) {
    const float* x  = (const float*)d_in[0];
    const float* s  = (const float*)d_in[1];
    const float* rd = (const float*)d_in[2];
    const float* sd = (const float*)d_in[3];
    const float* re = (const float*)d_in[4];
    const float* se = (const float*)d_in[5];

    char* ws = (char*)d_ws;
    const size_t SZT = (size_t)HW * CJ * 2;          // 42,467,328 B each
    u16*   CTt    = (u16*)ws;
    u16*   STt    = (u16*)(ws + SZT);
    float* sq6    = (float*)(ws + 2 * SZT);          // 6*HW floats
    float* inv6   = sq6 + 6 * HW;                    // 6*HW floats
    float* invbnj = inv6 + 6 * HW;                   // HW floats
    float* bestv  = invbnj + HW;                     // NS*HW floats
    int*   besti  = (int*)(bestv + (size_t)NS * HW);
    float* worstv = (float*)(besti + (size_t)NS * HW);
    int*   worsti = (int*)(worstv + (size_t)NS * HW);
    const size_t NEED = 2 * SZT + (size_t)(13 + 4 * NS) * HW * 4;
    if (ws_size < NEED) return;  // ws too small: fail loudly (wrong output)

    hipMemsetAsync(d_out, 0, sizeof(float), stream);

    k_transpose<<<dim3(HW / 32, CJ / 32), dim3(32, 8), 0, stream>>>(x, rd, re, CTt);
    k_transpose<<<dim3(HW / 32, CJ / 32), dim3(32, 8), 0, stream>>>(s, sd, se, STt);
    k_colsq<<<dim3(HW / 256, 6), 256, 0, stream>>>(x, s, rd, sd, re, se, sq6, inv6);
    k_joint<<<HW / 256, 256, 0, stream>>>(sq6, invbnj);
    k_gemm_arg<<<dim3(HW / BM, NS), 256, 0, stream>>>(CTt, STt, invbnj, bestv, besti, worstv, worsti);
    k_final<<<HW / 4, 256, 0, stream>>>(CTt, STt, inv6, bestv, besti, worstv, worsti, (float*)d_out);
}

// Round 7
// 779.626 us; speedup vs baseline: 1.6276x; 1.6276x over previous
//
#include <hip/hip_runtime.h>

typedef unsigned short u16;
typedef unsigned int u32;
using f32x4 = __attribute__((ext_vector_type(4))) float;
using bf16x8 = __attribute__((ext_vector_type(8))) short;

#define EPSF 1e-8f

constexpr int C1 = 768;
constexpr int HW = 9216;        // 96*96
constexpr int CJ = 2304;        // 3*768 joint channels
constexpr int NS = 36;          // col splits (9216/256)
constexpr int NTK = 72;         // K-tiles of 32 (2304/32), divisible by 3

__device__ __forceinline__ u16 f2bf(float f) {
    u32 u = __float_as_uint(f);
    u += 0x7FFFu + ((u >> 16) & 1u);   // RNE
    return (u16)(u >> 16);
}
__device__ __forceinline__ float bf2f(u16 h) {
    return __uint_as_float(((u32)h) << 16);
}

// async global->LDS DMA, 16B per lane. LDS dest = wave-uniform base + lane*16.
__device__ __forceinline__ void gl_lds16(const u16* g, u16* l) {
    __builtin_amdgcn_global_load_lds(
        (const __attribute__((address_space(1))) void*)g,
        (__attribute__((address_space(3))) void*)l, 16, 0, 0);
}

// ---------------- transpose + fp32->bf16: out[j][c] = in[c][j] ----------------
__global__ void k_transpose(const float* __restrict__ s0, const float* __restrict__ s1,
                            const float* __restrict__ s2, u16* __restrict__ dst) {
    __shared__ float tile[32][33];
    const int j0 = blockIdx.x * 32;
    const int c0 = blockIdx.y * 32;
    const int tx = threadIdx.x, ty = threadIdx.y;
    const int seg = (c0 >= 1536) ? 2 : (c0 >= 768) ? 1 : 0;   // 768 not pow2: no & trick
    const float* src = (seg == 0) ? s0 : (seg == 1) ? s1 : s2;
    const int cb = c0 - seg * 768;
#pragma unroll
    for (int r = 0; r < 4; ++r) {
        int cc = ty + r * 8;
        tile[cc][tx] = src[(size_t)(cb + cc) * HW + j0 + tx];
    }
    __syncthreads();
#pragma unroll
    for (int r = 0; r < 4; ++r) {
        int jj = ty + r * 8;
        dst[(size_t)(j0 + jj) * CJ + c0 + tx] = f2bf(tile[tx][jj]);
    }
}

// ---------------- per-column squared sums + 1/(sqrt(s)+eps) for all 6 mats ----------------
__global__ void k_colsq(const float* __restrict__ p0, const float* __restrict__ p1,
                        const float* __restrict__ p2, const float* __restrict__ p3,
                        const float* __restrict__ p4, const float* __restrict__ p5,
                        float* __restrict__ sq, float* __restrict__ inv) {
    const float* src;
    switch (blockIdx.y) {
        case 0: src = p0; break; case 1: src = p1; break; case 2: src = p2; break;
        case 3: src = p3; break; case 4: src = p4; break; default: src = p5; break;
    }
    const int j = blockIdx.x * 256 + threadIdx.x;
    float s = 0.f;
#pragma unroll 8
    for (int c = 0; c < C1; ++c) {
        float v = src[(size_t)c * HW + j];
        s = fmaf(v, v, s);
    }
    sq[blockIdx.y * HW + j] = s;
    inv[blockIdx.y * HW + j] = 1.0f / (sqrtf(s) + EPSF);
}

// ---------------- joint style norm: 1/(sqrt(s1+s3+s5+EPS)+EPS) ----------------
__global__ void k_joint(const float* __restrict__ sq, float* __restrict__ invbnj) {
    const int j = blockIdx.x * 256 + threadIdx.x;
    float s = sq[1 * HW + j] + sq[3 * HW + j] + sq[5 * HW + j];
    invbnj[j] = 1.0f / (sqrtf(s + EPSF) + EPSF);
}

// ---------------- fused GEMM (G = CT^T*ST via bf16 MFMA) + per-row arg best/worst ----------------
// Round 7: 256x256 tile, BK=32, 8 waves (2Mx4N), TRI-buffered LDS with counted
// vmcnt(4) + raw s_barrier (T3/T4: loads span 2 compute phases, never drained to 0).
// Swizzle slot^=((row>>1)&3) applied on global source AND ds_read (rule #21).
__global__ __launch_bounds__(512, 2) void k_gemm_arg(
    const u16* __restrict__ CT, const u16* __restrict__ ST,
    const float* __restrict__ invbn,
    float* __restrict__ bestv, int* __restrict__ besti,
    float* __restrict__ worstv, int* __restrict__ worsti) {
    __shared__ u16 ldsA0[256 * 32], ldsA1[256 * 32], ldsA2[256 * 32];
    __shared__ u16 ldsB0[256 * 32], ldsB1[256 * 32], ldsB2[256 * 32];
    __shared__ float s_bv[4][256]; __shared__ int s_bi[4][256];
    __shared__ float s_wv[4][256]; __shared__ int s_wi[4][256];

    const int tid = threadIdx.x;
    const int l = tid & 63;
    const int w = tid >> 6;          // 0..7
    const int wr = w >> 2;           // 0..1  (M half)
    const int wc = w & 3;            // 0..3  (N quarter)
    const int rowbase = blockIdx.x * 256;
    const int colbase = blockIdx.y * 256;

    for (int i = tid; i < 1024; i += 512) {
        ((float*)s_bv)[i] = -3.4e38f; ((int*)s_bi)[i] = 0x7fffffff;
        ((float*)s_wv)[i] =  3.4e38f; ((int*)s_wi)[i] = 0x7fffffff;
    }

    // ---- staging geometry: per K-tile (256 rows x 32 k, A and B) = 4 gl_lds/thread.
    // Wave w, chunk j in {0,1}: rows [(w*2+j)*16, +16). Lane l: row +(l>>2), slot l&3.
    // Global slot pre-swizzled: sslot = (l&3) ^ ((l>>3)&3)  ( == (l&3) ^ ((row>>1)&3) ).
    const int srow = l >> 2;
    const int sslot = (l & 3) ^ ((l >> 3) & 3);
    const int r0 = (w * 2 + 0) * 16 + srow;
    const int r1 = (w * 2 + 1) * 16 + srow;
    const u16* gA0 = CT + (size_t)(rowbase + r0) * CJ + sslot * 8;
    const u16* gA1 = CT + (size_t)(rowbase + r1) * CJ + sslot * 8;
    const u16* gB0 = ST + (size_t)(colbase + r0) * CJ + sslot * 8;
    const u16* gB1 = ST + (size_t)(colbase + r1) * CJ + sslot * 8;
    const int lo0 = (w * 2 + 0) * 16 * 32;   // wave-uniform LDS elem offsets
    const int lo1 = (w * 2 + 1) * 16 * 32;

    // ---- fragment read geometry (swizzled ds_read_b128)
    const int frow = l & 15;
    const int fk = l >> 4;
    const int sl = fk ^ ((frow >> 1) & 3);           // lane-constant slot
    const int abase = (wr * 128 + frow) * 32 + sl * 8;
    const int bbase = (wc * 64 + frow) * 32 + sl * 8;

    f32x4 acc[8][4];
    const f32x4 fzero = {0.f, 0.f, 0.f, 0.f};
#pragma unroll
    for (int M = 0; M < 8; ++M)
#pragma unroll
        for (int N = 0; N < 4; ++N) acc[M][N] = fzero;

#define STAGE(At, Bt, kt) { const size_t ko = (size_t)(kt) * 32;            \
        gl_lds16(gA0 + ko, (At) + lo0); gl_lds16(gA1 + ko, (At) + lo1);     \
        gl_lds16(gB0 + ko, (Bt) + lo0); gl_lds16(gB1 + ko, (Bt) + lo1); }

#define COMPUTE(Ab, Bb) {                                                   \
        bf16x8 af[8], bfr[4];                                               \
        _Pragma("unroll")                                                   \
        for (int M = 0; M < 8; ++M) af[M] = *(const bf16x8*)((Ab) + abase + M * 16 * 32); \
        _Pragma("unroll")                                                   \
        for (int N = 0; N < 4; ++N) bfr[N] = *(const bf16x8*)((Bb) + bbase + N * 16 * 32); \
        __builtin_amdgcn_s_setprio(1);                                      \
        _Pragma("unroll")                                                   \
        for (int M = 0; M < 8; ++M)                                         \
            _Pragma("unroll")                                               \
            for (int N = 0; N < 4; ++N)                                     \
                acc[M][N] = __builtin_amdgcn_mfma_f32_16x16x32_bf16(af[M], bfr[N], acc[M][N], 0, 0, 0); \
        __builtin_amdgcn_s_setprio(0); }

#define TILE(cA, cB, sA, sB, st) {                                          \
        asm volatile("s_waitcnt vmcnt(4)" ::: "memory");                    \
        __builtin_amdgcn_s_barrier();                                       \
        __builtin_amdgcn_sched_barrier(0);                                  \
        if ((st) < NTK) STAGE(sA, sB, st);                                  \
        __builtin_amdgcn_sched_barrier(0);                                  \
        COMPUTE(cA, cB); }

    STAGE(ldsA0, ldsB0, 0);
    STAGE(ldsA1, ldsB1, 1);
#pragma unroll 1
    for (int t = 0; t < NTK; t += 3) {
        TILE(ldsA0, ldsB0, ldsA2, ldsB2, t + 2);
        TILE(ldsA1, ldsB1, ldsA0, ldsB0, t + 3);
        TILE(ldsA2, ldsB2, ldsA1, ldsB1, t + 4);
    }
#undef TILE
#undef COMPUTE
#undef STAGE

    // ---- epilogue: score = G * invbn[col]; per-row best/worst ----
    float ib[4];
#pragma unroll
    for (int N = 0; N < 4; ++N) ib[N] = invbn[colbase + wc * 64 + N * 16 + frow];

#pragma unroll
    for (int M = 0; M < 8; ++M) {
#pragma unroll
        for (int i = 0; i < 4; ++i) {
            float bv = -3.4e38f, wv = 3.4e38f; int bi = 0x7fffffff, wi = 0x7fffffff;
#pragma unroll
            for (int N = 0; N < 4; ++N) {
                float sc = acc[M][N][i] * ib[N];
                int ci = colbase + wc * 64 + N * 16 + frow;
                if (sc > bv) { bv = sc; bi = ci; }
                if (sc < wv) { wv = sc; wi = ci; }
            }
#pragma unroll
            for (int d = 1; d < 16; d <<= 1) {   // reduce across the 16 frow lanes
                float obv = __shfl_xor(bv, d); int obi = __shfl_xor(bi, d);
                if (obv > bv || (obv == bv && obi < bi)) { bv = obv; bi = obi; }
                float owv = __shfl_xor(wv, d); int owi = __shfl_xor(wi, d);
                if (owv < wv || (owv == wv && owi < wi)) { wv = owv; wi = owi; }
            }
            if ((l & 15) == 0) {
                int rl = wr * 128 + M * 16 + (l >> 4) * 4 + i;
                if (bv > s_bv[wc][rl] || (bv == s_bv[wc][rl] && bi < s_bi[wc][rl])) { s_bv[wc][rl] = bv; s_bi[wc][rl] = bi; }
                if (wv < s_wv[wc][rl] || (wv == s_wv[wc][rl] && wi < s_wi[wc][rl])) { s_wv[wc][rl] = wv; s_wi[wc][rl] = wi; }
            }
        }
    }

    __syncthreads();
    if (tid < 256) {
        float bv = s_bv[0][tid]; int bi = s_bi[0][tid];
        float wv = s_wv[0][tid]; int wi = s_wi[0][tid];
#pragma unroll
        for (int c = 1; c < 4; ++c) {
            if (s_bv[c][tid] > bv || (s_bv[c][tid] == bv && s_bi[c][tid] < bi)) { bv = s_bv[c][tid]; bi = s_bi[c][tid]; }
            if (s_wv[c][tid] < wv || (s_wv[c][tid] == wv && s_wi[c][tid] < wi)) { wv = s_wv[c][tid]; wi = s_wi[c][tid]; }
        }
        const int sp = blockIdx.y;
        bestv [(size_t)sp * HW + rowbase + tid] = bv;
        besti [(size_t)sp * HW + rowbase + tid] = bi;
        worstv[(size_t)sp * HW + rowbase + tid] = wv;
        worsti[(size_t)sp * HW + rowbase + tid] = wi;
    }
}

// ---------------- final: reduce splits, gathered cosines, loss ----------------
__global__ void k_final(const u16* __restrict__ CT, const u16* __restrict__ ST,
                        const float* __restrict__ inv6,
                        const float* __restrict__ bestv, const int* __restrict__ besti,
                        const float* __restrict__ worstv, const int* __restrict__ worsti,
                        float* __restrict__ out) {
    const int w = threadIdx.x >> 6, l = threadIdx.x & 63;
    const int r = blockIdx.x * 4 + w;

    float bv = -3.4e38f, wv = 3.4e38f; int bi = 0x7fffffff, wi = 0x7fffffff;
    if (l < NS) {
        bv = bestv [(size_t)l * HW + r]; bi = besti [(size_t)l * HW + r];
        wv = worstv[(size_t)l * HW + r]; wi = worsti[(size_t)l * HW + r];
    }
#pragma unroll
    for (int d = 1; d < 64; d <<= 1) {
        float obv = __shfl_xor(bv, d); int obi = __shfl_xor(bi, d);
        if (obv > bv || (obv == bv && obi < bi)) { bv = obv; bi = obi; }
        float owv = __shfl_xor(wv, d); int owi = __shfl_xor(wi, d);
        if (owv < wv || (owv == wv && owi < wi)) { wv = owv; wi = owi; }
    }
    const int zb = bi, zw = wi;

    const u16* ar = CT + (size_t)r * CJ;
    const u16* bb = ST + (size_t)zb * CJ;
    const u16* bw = ST + (size_t)zw * CJ;
    float db[3] = {0.f, 0.f, 0.f}, dw[3] = {0.f, 0.f, 0.f};
#pragma unroll
    for (int it = 0; it < 9; ++it) {
        const int c = it * 256 + l * 4;
        uint2 va = *(const uint2*)(ar + c);
        uint2 vb = *(const uint2*)(bb + c);
        uint2 vw = *(const uint2*)(bw + c);
        const int seg = it / 3;  // 0: feats, 1: depth, 2: edge (768 = 3*256)
        float a0 = bf2f((u16)(va.x & 0xffff)), a1 = bf2f((u16)(va.x >> 16));
        float a2 = bf2f((u16)(va.y & 0xffff)), a3 = bf2f((u16)(va.y >> 16));
        float b0 = bf2f((u16)(vb.x & 0xffff)), b1 = bf2f((u16)(vb.x >> 16));
        float b2 = bf2f((u16)(vb.y & 0xffff)), b3 = bf2f((u16)(vb.y >> 16));
        float w0 = bf2f((u16)(vw.x & 0xffff)), w1 = bf2f((u16)(vw.x >> 16));
        float w2 = bf2f((u16)(vw.y & 0xffff)), w3 = bf2f((u16)(vw.y >> 16));
        db[seg] += a0 * b0 + a1 * b1 + a2 * b2 + a3 * b3;
        dw[seg] += a0 * w0 + a1 * w1 + a2 * w2 + a3 * w3;
    }
#pragma unroll
    for (int d = 1; d < 64; d <<= 1) {
#pragma unroll
        for (int s = 0; s < 3; ++s) {
            db[s] += __shfl_xor(db[s], d);
            dw[s] += __shfl_xor(dw[s], d);
        }
    }
    if (l == 0) {
        float c0 = db[0] * inv6[0 * HW + r] * inv6[1 * HW + zb];
        float c1 = db[1] * inv6[2 * HW + r] * inv6[3 * HW + zb];
        float c2 = db[2] * inv6[4 * HW + r] * inv6[5 * HW + zb];
        float d0 = dw[0] * inv6[0 * HW + r] * inv6[1 * HW + zw];
        float d1 = dw[1] * inv6[2 * HW + r] * inv6[3 * HW + zw];
        float d2 = dw[2] * inv6[4 * HW + r] * inv6[5 * HW + zw];
        float contrib = (6.0f - c0 - c1 - c2 + d0 + d1 + d2) * (1.0f / 9216.0f);
        atomicAdd(out, contrib);
    }
}

extern "C" void kernel_launch(void* const* d_in, const int* in_sizes, int n_in,
                              void* d_out, int out_size, void* d_ws, size_t ws_size,
                              hipStream_t stream) {
    const float* x  = (const float*)d_in[0];
    const float* s  = (const float*)d_in[1];
    const float* rd = (const float*)d_in[2];
    const float* sd = (const float*)d_in[3];
    const float* re = (const float*)d_in[4];
    const float* se = (const float*)d_in[5];

    char* ws = (char*)d_ws;
    const size_t SZT = (size_t)HW * CJ * 2;          // 42,467,328 B each
    u16*   CTt    = (u16*)ws;
    u16*   STt    = (u16*)(ws + SZT);
    float* sq6    = (float*)(ws + 2 * SZT);          // 6*HW floats
    float* inv6   = sq6 + 6 * HW;                    // 6*HW floats
    float* invbnj = inv6 + 6 * HW;                   // HW floats
    float* bestv  = invbnj + HW;                     // NS*HW floats
    int*   besti  = (int*)(bestv + (size_t)NS * HW);
    float* worstv = (float*)(besti + (size_t)NS * HW);
    int*   worsti = (int*)(worstv + (size_t)NS * HW);
    const size_t NEED = 2 * SZT + (size_t)(13 + 4 * NS) * HW * 4;
    if (ws_size < NEED) return;  // ws too small: fail loudly (wrong output)

    hipMemsetAsync(d_out, 0, sizeof(float), stream);

    k_transpose<<<dim3(HW / 32, CJ / 32), dim3(32, 8), 0, stream>>>(x, rd, re, CTt);
    k_transpose<<<dim3(HW / 32, CJ / 32), dim3(32, 8), 0, stream>>>(s, sd, se, STt);
    k_colsq<<<dim3(HW / 256, 6), 256, 0, stream>>>(x, s, rd, sd, re, se, sq6, inv6);
    k_joint<<<HW / 256, 256, 0, stream>>>(sq6, invbnj);
    k_gemm_arg<<<dim3(HW / 256, NS), 512, 0, stream>>>(CTt, STt, invbnj, bestv, besti, worstv, worsti);
    k_final<<<HW / 4, 256, 0, stream>>>(CTt, STt, inv6, bestv, besti, worstv, worsti, (float*)d_out);
}

// Round 8
// 760.024 us; speedup vs baseline: 1.6696x; 1.0258x over previous
//
#include <hip/hip_runtime.h>

typedef unsigned short u16;
typedef unsigned int u32;
using f32x4 = __attribute__((ext_vector_type(4))) float;
using bf16x8 = __attribute__((ext_vector_type(8))) short;

#define EPSF 1e-8f

constexpr int C1 = 768;
constexpr int HW = 9216;        // 96*96
constexpr int CJ = 2304;        // 3*768 joint channels
constexpr int NS = 36;          // col splits (9216/256)
constexpr int NTK = 72;         // K-tiles of 32 (2304/32), divisible by 4

__device__ __forceinline__ u16 f2bf(float f) {
    u32 u = __float_as_uint(f);
    u += 0x7FFFu + ((u >> 16) & 1u);   // RNE
    return (u16)(u >> 16);
}
__device__ __forceinline__ float bf2f(u16 h) {
    return __uint_as_float(((u32)h) << 16);
}

// async global->LDS DMA, 16B per lane. LDS dest = wave-uniform base + lane*16.
__device__ __forceinline__ void gl_lds16(const u16* g, u16* l) {
    __builtin_amdgcn_global_load_lds(
        (const __attribute__((address_space(1))) void*)g,
        (__attribute__((address_space(3))) void*)l, 16, 0, 0);
}

// ---------------- transpose + fp32->bf16: out[j][c] = in[c][j] ----------------
__global__ void k_transpose(const float* __restrict__ s0, const float* __restrict__ s1,
                            const float* __restrict__ s2, u16* __restrict__ dst) {
    __shared__ float tile[32][33];
    const int j0 = blockIdx.x * 32;
    const int c0 = blockIdx.y * 32;
    const int tx = threadIdx.x, ty = threadIdx.y;
    const int seg = (c0 >= 1536) ? 2 : (c0 >= 768) ? 1 : 0;   // 768 not pow2: no & trick
    const float* src = (seg == 0) ? s0 : (seg == 1) ? s1 : s2;
    const int cb = c0 - seg * 768;
#pragma unroll
    for (int r = 0; r < 4; ++r) {
        int cc = ty + r * 8;
        tile[cc][tx] = src[(size_t)(cb + cc) * HW + j0 + tx];
    }
    __syncthreads();
#pragma unroll
    for (int r = 0; r < 4; ++r) {
        int jj = ty + r * 8;
        dst[(size_t)(j0 + jj) * CJ + c0 + tx] = f2bf(tile[tx][jj]);
    }
}

// ---------------- per-column squared sums + 1/(sqrt(s)+eps) for all 6 mats ----------------
__global__ void k_colsq(const float* __restrict__ p0, const float* __restrict__ p1,
                        const float* __restrict__ p2, const float* __restrict__ p3,
                        const float* __restrict__ p4, const float* __restrict__ p5,
                        float* __restrict__ sq, float* __restrict__ inv) {
    const float* src;
    switch (blockIdx.y) {
        case 0: src = p0; break; case 1: src = p1; break; case 2: src = p2; break;
        case 3: src = p3; break; case 4: src = p4; break; default: src = p5; break;
    }
    const int j = blockIdx.x * 256 + threadIdx.x;
    float s = 0.f;
#pragma unroll 8
    for (int c = 0; c < C1; ++c) {
        float v = src[(size_t)c * HW + j];
        s = fmaf(v, v, s);
    }
    sq[blockIdx.y * HW + j] = s;
    inv[blockIdx.y * HW + j] = 1.0f / (sqrtf(s) + EPSF);
}

// ---------------- joint style norm: 1/(sqrt(s1+s3+s5+EPS)+EPS) ----------------
__global__ void k_joint(const float* __restrict__ sq, float* __restrict__ invbnj) {
    const int j = blockIdx.x * 256 + threadIdx.x;
    float s = sq[1 * HW + j] + sq[3 * HW + j] + sq[5 * HW + j];
    invbnj[j] = 1.0f / (sqrtf(s + EPSF) + EPSF);
}

// ---------------- fused GEMM (G = CT^T*ST via bf16 MFMA) + per-row arg best/worst ----------------
// Round 8: QUAD-buffered LDS (depth-3 pipeline: loads span ~3 compute phases,
// > worst-case HBM latency), counted vmcnt(8), raw s_barrier, clamped tail
// stages (uniform outstanding count -> every vmcnt provably retires the tile
// about to be computed; fixes round-7's vacuous-wait tail race).
__global__ __launch_bounds__(512, 2) void k_gemm_arg(
    const u16* __restrict__ CT, const u16* __restrict__ ST,
    const float* __restrict__ invbn,
    float* __restrict__ bestv, int* __restrict__ besti,
    float* __restrict__ worstv, int* __restrict__ worsti) {
    __shared__ u16 ldsA0[256 * 32], ldsA1[256 * 32], ldsA2[256 * 32], ldsA3[256 * 32];
    __shared__ u16 ldsB0[256 * 32], ldsB1[256 * 32], ldsB2[256 * 32], ldsB3[256 * 32];
    __shared__ float s_bv[4][256]; __shared__ int s_bi[4][256];
    __shared__ float s_wv[4][256]; __shared__ int s_wi[4][256];

    const int tid = threadIdx.x;
    const int l = tid & 63;
    const int w = tid >> 6;          // 0..7
    const int wr = w >> 2;           // 0..1  (M half)
    const int wc = w & 3;            // 0..3  (N quarter)
    const int rowbase = blockIdx.x * 256;
    const int colbase = blockIdx.y * 256;

    for (int i = tid; i < 1024; i += 512) {
        ((float*)s_bv)[i] = -3.4e38f; ((int*)s_bi)[i] = 0x7fffffff;
        ((float*)s_wv)[i] =  3.4e38f; ((int*)s_wi)[i] = 0x7fffffff;
    }

    // ---- staging geometry: per K-tile (256 rows x 32 k, A and B) = 4 gl_lds/thread.
    // Wave w, chunk j in {0,1}: rows [(w*2+j)*16, +16). Lane l: row +(l>>2), slot l&3.
    // Global slot pre-swizzled: sslot = (l&3) ^ ((l>>3)&3)  ( == (l&3) ^ ((row>>1)&3) ).
    const int srow = l >> 2;
    const int sslot = (l & 3) ^ ((l >> 3) & 3);
    const int r0 = (w * 2 + 0) * 16 + srow;
    const int r1 = (w * 2 + 1) * 16 + srow;
    const u16* gA0 = CT + (size_t)(rowbase + r0) * CJ + sslot * 8;
    const u16* gA1 = CT + (size_t)(rowbase + r1) * CJ + sslot * 8;
    const u16* gB0 = ST + (size_t)(colbase + r0) * CJ + sslot * 8;
    const u16* gB1 = ST + (size_t)(colbase + r1) * CJ + sslot * 8;
    const int lo0 = (w * 2 + 0) * 16 * 32;   // wave-uniform LDS elem offsets
    const int lo1 = (w * 2 + 1) * 16 * 32;

    // ---- fragment read geometry (swizzled ds_read_b128)
    const int frow = l & 15;
    const int fk = l >> 4;
    const int sl = fk ^ ((frow >> 1) & 3);           // lane-constant slot
    const int abase = (wr * 128 + frow) * 32 + sl * 8;
    const int bbase = (wc * 64 + frow) * 32 + sl * 8;

    f32x4 acc[8][4];
    const f32x4 fzero = {0.f, 0.f, 0.f, 0.f};
#pragma unroll
    for (int M = 0; M < 8; ++M)
#pragma unroll
        for (int N = 0; N < 4; ++N) acc[M][N] = fzero;

#define STAGE(At, Bt, kt) { const size_t ko = (size_t)(kt) * 32;            \
        gl_lds16(gA0 + ko, (At) + lo0); gl_lds16(gA1 + ko, (At) + lo1);     \
        gl_lds16(gB0 + ko, (Bt) + lo0); gl_lds16(gB1 + ko, (Bt) + lo1); }

#define COMPUTE(Ab, Bb) {                                                   \
        bf16x8 af[8], bfr[4];                                               \
        _Pragma("unroll")                                                   \
        for (int M = 0; M < 8; ++M) af[M] = *(const bf16x8*)((Ab) + abase + M * 16 * 32); \
        _Pragma("unroll")                                                   \
        for (int N = 0; N < 4; ++N) bfr[N] = *(const bf16x8*)((Bb) + bbase + N * 16 * 32); \
        __builtin_amdgcn_s_setprio(1);                                      \
        _Pragma("unroll")                                                   \
        for (int M = 0; M < 8; ++M)                                         \
            _Pragma("unroll")                                               \
            for (int N = 0; N < 4; ++N)                                     \
                acc[M][N] = __builtin_amdgcn_mfma_f32_16x16x32_bf16(af[M], bfr[N], acc[M][N], 0, 0, 0); \
        __builtin_amdgcn_s_setprio(0); }

    // clamped stage index: tail re-stages tile NTK-1 into dead buffers so the
    // per-thread outstanding-load count stays uniform (12) -> vmcnt(8) always
    // retires exactly the tile about to be computed.
#define TILE(cA, cB, sA, sB, st) {                                          \
        asm volatile("s_waitcnt vmcnt(8)" ::: "memory");                    \
        __builtin_amdgcn_s_barrier();                                       \
        __builtin_amdgcn_sched_barrier(0);                                  \
        { const int stc = (st) < NTK ? (st) : NTK - 1; STAGE(sA, sB, stc); }\
        __builtin_amdgcn_sched_barrier(0);                                  \
        COMPUTE(cA, cB); }

    STAGE(ldsA0, ldsB0, 0);
    STAGE(ldsA1, ldsB1, 1);
    STAGE(ldsA2, ldsB2, 2);
#pragma unroll 1
    for (int t = 0; t < NTK; t += 4) {
        TILE(ldsA0, ldsB0, ldsA3, ldsB3, t + 3);
        TILE(ldsA1, ldsB1, ldsA0, ldsB0, t + 4);
        TILE(ldsA2, ldsB2, ldsA1, ldsB1, t + 5);
        TILE(ldsA3, ldsB3, ldsA2, ldsB2, t + 6);
    }
#undef TILE
#undef COMPUTE
#undef STAGE

    // ---- epilogue: score = G * invbn[col]; per-row best/worst ----
    float ib[4];
#pragma unroll
    for (int N = 0; N < 4; ++N) ib[N] = invbn[colbase + wc * 64 + N * 16 + frow];

#pragma unroll
    for (int M = 0; M < 8; ++M) {
#pragma unroll
        for (int i = 0; i < 4; ++i) {
            float bv = -3.4e38f, wv = 3.4e38f; int bi = 0x7fffffff, wi = 0x7fffffff;
#pragma unroll
            for (int N = 0; N < 4; ++N) {
                float sc = acc[M][N][i] * ib[N];
                int ci = colbase + wc * 64 + N * 16 + frow;
                if (sc > bv) { bv = sc; bi = ci; }
                if (sc < wv) { wv = sc; wi = ci; }
            }
#pragma unroll
            for (int d = 1; d < 16; d <<= 1) {   // reduce across the 16 frow lanes
                float obv = __shfl_xor(bv, d); int obi = __shfl_xor(bi, d);
                if (obv > bv || (obv == bv && obi < bi)) { bv = obv; bi = obi; }
                float owv = __shfl_xor(wv, d); int owi = __shfl_xor(wi, d);
                if (owv < wv || (owv == wv && owi < wi)) { wv = owv; wi = owi; }
            }
            if ((l & 15) == 0) {
                int rl = wr * 128 + M * 16 + (l >> 4) * 4 + i;
                if (bv > s_bv[wc][rl] || (bv == s_bv[wc][rl] && bi < s_bi[wc][rl])) { s_bv[wc][rl] = bv; s_bi[wc][rl] = bi; }
                if (wv < s_wv[wc][rl] || (wv == s_wv[wc][rl] && wi < s_wi[wc][rl])) { s_wv[wc][rl] = wv; s_wi[wc][rl] = wi; }
            }
        }
    }

    __syncthreads();
    if (tid < 256) {
        float bv = s_bv[0][tid]; int bi = s_bi[0][tid];
        float wv = s_wv[0][tid]; int wi = s_wi[0][tid];
#pragma unroll
        for (int c = 1; c < 4; ++c) {
            if (s_bv[c][tid] > bv || (s_bv[c][tid] == bv && s_bi[c][tid] < bi)) { bv = s_bv[c][tid]; bi = s_bi[c][tid]; }
            if (s_wv[c][tid] < wv || (s_wv[c][tid] == wv && s_wi[c][tid] < wi)) { wv = s_wv[c][tid]; wi = s_wi[c][tid]; }
        }
        const int sp = blockIdx.y;
        bestv [(size_t)sp * HW + rowbase + tid] = bv;
        besti [(size_t)sp * HW + rowbase + tid] = bi;
        worstv[(size_t)sp * HW + rowbase + tid] = wv;
        worsti[(size_t)sp * HW + rowbase + tid] = wi;
    }
}

// ---------------- final: reduce splits, gathered cosines, loss ----------------
__global__ void k_final(const u16* __restrict__ CT, const u16* __restrict__ ST,
                        const float* __restrict__ inv6,
                        const float* __restrict__ bestv, const int* __restrict__ besti,
                        const float* __restrict__ worstv, const int* __restrict__ worsti,
                        float* __restrict__ out) {
    const int w = threadIdx.x >> 6, l = threadIdx.x & 63;
    const int r = blockIdx.x * 4 + w;

    float bv = -3.4e38f, wv = 3.4e38f; int bi = 0x7fffffff, wi = 0x7fffffff;
    if (l < NS) {
        bv = bestv [(size_t)l * HW + r]; bi = besti [(size_t)l * HW + r];
        wv = worstv[(size_t)l * HW + r]; wi = worsti[(size_t)l * HW + r];
    }
#pragma unroll
    for (int d = 1; d < 64; d <<= 1) {
        float obv = __shfl_xor(bv, d); int obi = __shfl_xor(bi, d);
        if (obv > bv || (obv == bv && obi < bi)) { bv = obv; bi = obi; }
        float owv = __shfl_xor(wv, d); int owi = __shfl_xor(wi, d);
        if (owv < wv || (owv == wv && owi < wi)) { wv = owv; wi = owi; }
    }
    const int zb = bi, zw = wi;

    const u16* ar = CT + (size_t)r * CJ;
    const u16* bb = ST + (size_t)zb * CJ;
    const u16* bw = ST + (size_t)zw * CJ;
    float db[3] = {0.f, 0.f, 0.f}, dw[3] = {0.f, 0.f, 0.f};
#pragma unroll
    for (int it = 0; it < 9; ++it) {
        const int c = it * 256 + l * 4;
        uint2 va = *(const uint2*)(ar + c);
        uint2 vb = *(const uint2*)(bb + c);
        uint2 vw = *(const uint2*)(bw + c);
        const int seg = it / 3;  // 0: feats, 1: depth, 2: edge (768 = 3*256)
        float a0 = bf2f((u16)(va.x & 0xffff)), a1 = bf2f((u16)(va.x >> 16));
        float a2 = bf2f((u16)(va.y & 0xffff)), a3 = bf2f((u16)(va.y >> 16));
        float b0 = bf2f((u16)(vb.x & 0xffff)), b1 = bf2f((u16)(vb.x >> 16));
        float b2 = bf2f((u16)(vb.y & 0xffff)), b3 = bf2f((u16)(vb.y >> 16));
        float w0 = bf2f((u16)(vw.x & 0xffff)), w1 = bf2f((u16)(vw.x >> 16));
        float w2 = bf2f((u16)(vw.y & 0xffff)), w3 = bf2f((u16)(vw.y >> 16));
        db[seg] += a0 * b0 + a1 * b1 + a2 * b2 + a3 * b3;
        dw[seg] += a0 * w0 + a1 * w1 + a2 * w2 + a3 * w3;
    }
#pragma unroll
    for (int d = 1; d < 64; d <<= 1) {
#pragma unroll
        for (int s = 0; s < 3; ++s) {
            db[s] += __shfl_xor(db[s], d);
            dw[s] += __shfl_xor(dw[s], d);
        }
    }
    if (l == 0) {
        float c0 = db[0] * inv6[0 * HW + r] * inv6[1 * HW + zb];
        float c1 = db[1] * inv6[2 * HW + r] * inv6[3 * HW + zb];
        float c2 = db[2] * inv6[4 * HW + r] * inv6[5 * HW + zb];
        float d0 = dw[0] * inv6[0 * HW + r] * inv6[1 * HW + zw];
        float d1 = dw[1] * inv6[2 * HW + r] * inv6[3 * HW + zw];
        float d2 = dw[2] * inv6[4 * HW + r] * inv6[5 * HW + zw];
        float contrib = (6.0f - c0 - c1 - c2 + d0 + d1 + d2) * (1.0f / 9216.0f);
        atomicAdd(out, contrib);
    }
}

extern "C" void kernel_launch(void* const* d_in, const int* in_sizes, int n_in,
                              void* d_out, int out_size, void* d_ws, size_t ws_size,
                              hipStream_t stream) {
    const float* x  = (const float*)d_in[0];
    const float* s  = (const float*)d_in[1];
    const float* rd = (const float*)d_in[2];
    const float* sd = (const float*)d_in[3];
    const float* re = (const float*)d_in[4];
    const float* se = (const float*)d_in[5];

    char* ws = (char*)d_ws;
    const size_t SZT = (size_t)HW * CJ * 2;          // 42,467,328 B each
    u16*   CTt    = (u16*)ws;
    u16*   STt    = (u16*)(ws + SZT);
    float* sq6    = (float*)(ws + 2 * SZT);          // 6*HW floats
    float* inv6   = sq6 + 6 * HW;                    // 6*HW floats
    float* invbnj = inv6 + 6 * HW;                   // HW floats
    float* bestv  = invbnj + HW;                     // NS*HW floats
    int*   besti  = (int*)(bestv + (size_t)NS * HW);
    float* worstv = (float*)(besti + (size_t)NS * HW);
    int*   worsti = (int*)(worstv + (size_t)NS * HW);
    const size_t NEED = 2 * SZT + (size_t)(13 + 4 * NS) * HW * 4;
    if (ws_size < NEED) return;  // ws too small: fail loudly (wrong output)

    hipMemsetAsync(d_out, 0, sizeof(float), stream);

    k_transpose<<<dim3(HW / 32, CJ / 32), dim3(32, 8), 0, stream>>>(x, rd, re, CTt);
    k_transpose<<<dim3(HW / 32, CJ / 32), dim3(32, 8), 0, stream>>>(s, sd, se, STt);
    k_colsq<<<dim3(HW / 256, 6), 256, 0, stream>>>(x, s, rd, sd, re, se, sq6, inv6);
    k_joint<<<HW / 256, 256, 0, stream>>>(sq6, invbnj);
    k_gemm_arg<<<dim3(HW / 256, NS), 512, 0, stream>>>(CTt, STt, invbnj, bestv, besti, worstv, worsti);
    k_final<<<HW / 4, 256, 0, stream>>>(CTt, STt, inv6, bestv, besti, worstv, worsti, (float*)d_out);
}

// Round 9
// 577.742 us; speedup vs baseline: 2.1963x; 1.3155x over previous
//
#include <hip/hip_runtime.h>

typedef unsigned char u8;
typedef unsigned short u16;
typedef unsigned int u32;
using f32x4 = __attribute__((ext_vector_type(4))) float;
using i32x8 = __attribute__((ext_vector_type(8))) int;

#define EPSF 1e-8f

constexpr int C1 = 768;
constexpr int HW = 9216;       // 96*96
constexpr int CJ = 2304;       // joint channels (= bytes/row in fp8)
constexpr int NS = 36;         // col splits (9216/256)
constexpr int NTKF = 18;       // K-tiles of 128 (2304/128), even

// async global->LDS DMA, 16B per lane. LDS dest = wave-uniform base + lane*16.
__device__ __forceinline__ void gl_lds16(const u8* g, u8* l) {
    __builtin_amdgcn_global_load_lds(
        (const __attribute__((address_space(1))) void*)g,
        (__attribute__((address_space(3))) void*)l, 16, 0, 0);
}

// e4m3fn -> f32 (no inf; NaN never occurs for our data)
__device__ __forceinline__ float e4m3f(u32 b) {
    u32 s = b >> 7, e = (b >> 3) & 15, m = b & 7;
    float mag = (e == 0) ? (float)m * 0.001953125f               // m * 2^-9
                         : __uint_as_float(((e + 120) << 23) | (m << 20));
    return s ? -mag : mag;
}

// ---------------- transpose + fp32->fp8(e4m3): out[j][c] = in[c][j] ----------------
__global__ void k_transpose8(const float* __restrict__ s0, const float* __restrict__ s1,
                             const float* __restrict__ s2, u8* __restrict__ dst) {
    __shared__ float tile[32][33];
    const int j0 = blockIdx.x * 32;
    const int c0 = blockIdx.y * 32;
    const int tx = threadIdx.x, ty = threadIdx.y;
    const int seg = (c0 >= 1536) ? 2 : (c0 >= 768) ? 1 : 0;   // 768 not pow2: no & trick
    const float* src = (seg == 0) ? s0 : (seg == 1) ? s1 : s2;
    const int cb = c0 - seg * 768;
#pragma unroll
    for (int r = 0; r < 4; ++r) {
        int cc = ty + r * 8;
        tile[cc][tx] = src[(size_t)(cb + cc) * HW + j0 + tx];
    }
    __syncthreads();
    // write 32j x 32c fp8 as 512 u16 stores (2 packed e4m3 per store), 2 iters
#pragma unroll
    for (int r = 0; r < 2; ++r) {
        int idx = r * 256 + ty * 32 + tx;       // 0..511
        int j = idx >> 4, cp = idx & 15;        // c-pair index
        int p = __builtin_amdgcn_cvt_pk_fp8_f32(tile[cp * 2][j], tile[cp * 2 + 1][j], 0, false);
        *(u16*)(dst + (size_t)(j0 + j) * CJ + c0 + cp * 2) = (u16)p;
    }
}

// ---------------- per-column squared sums + 1/(sqrt(s)+eps) for all 6 mats ----------------
__global__ void k_colsq(const float* __restrict__ p0, const float* __restrict__ p1,
                        const float* __restrict__ p2, const float* __restrict__ p3,
                        const float* __restrict__ p4, const float* __restrict__ p5,
                        float* __restrict__ sq, float* __restrict__ inv) {
    const float* src;
    switch (blockIdx.y) {
        case 0: src = p0; break; case 1: src = p1; break; case 2: src = p2; break;
        case 3: src = p3; break; case 4: src = p4; break; default: src = p5; break;
    }
    const int j = blockIdx.x * 256 + threadIdx.x;
    float s = 0.f;
#pragma unroll 8
    for (int c = 0; c < C1; ++c) {
        float v = src[(size_t)c * HW + j];
        s = fmaf(v, v, s);
    }
    sq[blockIdx.y * HW + j] = s;
    inv[blockIdx.y * HW + j] = 1.0f / (sqrtf(s) + EPSF);
}

// ---------------- joint style norm: 1/(sqrt(s1+s3+s5+EPS)+EPS) ----------------
__global__ void k_joint(const float* __restrict__ sq, float* __restrict__ invbnj) {
    const int j = blockIdx.x * 256 + threadIdx.x;
    float s = sq[1 * HW + j] + sq[3 * HW + j] + sq[5 * HW + j];
    invbnj[j] = 1.0f / (sqrtf(s + EPSF) + EPSF);
}

// ---------------- fused GEMM (G = CT^T*ST via MX-fp8 MFMA K=128) + per-row arg best/worst ----
// Round 9: e4m3 with unity MX scales. 256x256 tile, BK=128, 18 K-tiles, double-buffered
// LDS (2 x 64KB), counted vmcnt(8) + raw s_barrier; per-tile compute (~2200cy/CU) >>
// load latency, so depth-1 prefetch suffices. Swizzle slot^=(row&7) on 128B rows,
// applied on global source AND ds_read (rule #21). Epilogue/C-layout unchanged
// (C/D mapping is shape-determined, dtype-independent).
__global__ __launch_bounds__(512, 2) void k_gemm_arg(
    const u8* __restrict__ CT, const u8* __restrict__ ST,
    const float* __restrict__ invbn,
    float* __restrict__ bestv, int* __restrict__ besti,
    float* __restrict__ worstv, int* __restrict__ worsti) {
    __shared__ u8 ldsA0[256 * 128], ldsA1[256 * 128];
    __shared__ u8 ldsB0[256 * 128], ldsB1[256 * 128];
    __shared__ float s_bv[4][256]; __shared__ int s_bi[4][256];
    __shared__ float s_wv[4][256]; __shared__ int s_wi[4][256];

    const int tid = threadIdx.x;
    const int l = tid & 63;
    const int w = tid >> 6;          // 0..7
    const int wr = w >> 2;           // 0..1  (M half)
    const int wc = w & 3;            // 0..3  (N quarter)
    const int rowbase = blockIdx.x * 256;
    const int colbase = blockIdx.y * 256;

    for (int i = tid; i < 1024; i += 512) {
        ((float*)s_bv)[i] = -3.4e38f; ((int*)s_bi)[i] = 0x7fffffff;
        ((float*)s_wv)[i] =  3.4e38f; ((int*)s_wi)[i] = 0x7fffffff;
    }

    // ---- staging: per K-tile A,B = 256 rows x 128 B each. Wave w: rows [w*32,+32)
    // as 4 chunks of 8 rows (64 lanes x 16B = 1KB). Lane l: row +(l>>3), slot l&7.
    // Global slot pre-swizzled with the read-side involution: slot ^ (row&7), row&7 = l>>3.
    const int srow8 = l >> 3;
    const int sslot8 = (l & 7) ^ (l >> 3);
    const u8* gA = CT + (size_t)(rowbase + w * 32 + srow8) * CJ + sslot8 * 16;
    const u8* gB = ST + (size_t)(colbase + w * 32 + srow8) * CJ + sslot8 * 16;
    const int ldsbase = w * 32 * 128;   // wave-uniform

#define STAGE(Ab, Bb, kt) { const size_t ko = (size_t)(kt) * 128;             \
        _Pragma("unroll")                                                     \
        for (int c = 0; c < 4; ++c) {                                         \
            gl_lds16(gA + ko + (size_t)c * 8 * CJ, (Ab) + ldsbase + c * 1024);\
            gl_lds16(gB + ko + (size_t)c * 8 * CJ, (Bb) + ldsbase + c * 1024);} }

    // ---- fragment read geometry: lane l -> row(l&15), k-chunk (l>>4)*32 bytes,
    // read as two b128 at swizzled slots s0,s1 (order fixed by register halves).
    const int frow = l & 15;
    const int r7 = l & 7;
    const int s0 = (2 * (l >> 4)) ^ r7;
    const int s1 = (2 * (l >> 4) + 1) ^ r7;
    const int aoff = (wr * 128 + frow) * 128;   // + M*16*128
    const int boff = (wc * 64 + frow) * 128;    // + N*16*128

    f32x4 acc[8][4];
    const f32x4 fzero = {0.f, 0.f, 0.f, 0.f};
#pragma unroll
    for (int M = 0; M < 8; ++M)
#pragma unroll
        for (int N = 0; N < 4; ++N) acc[M][N] = fzero;

#define LDFRAG(dst, base) {                                                   \
        uint4 lo_ = *(const uint4*)((base) + s0 * 16);                        \
        uint4 hi_ = *(const uint4*)((base) + s1 * 16);                        \
        dst[0] = lo_.x; dst[1] = lo_.y; dst[2] = lo_.z; dst[3] = lo_.w;       \
        dst[4] = hi_.x; dst[5] = hi_.y; dst[6] = hi_.z; dst[7] = hi_.w; }

#define COMPUTE(Ab, Bb) {                                                     \
        i32x8 bfr[4], af[4];                                                  \
        _Pragma("unroll")                                                     \
        for (int N = 0; N < 4; ++N) LDFRAG(bfr[N], (Bb) + boff + N * 2048);   \
        _Pragma("unroll")                                                     \
        for (int M = 0; M < 4; ++M) LDFRAG(af[M], (Ab) + aoff + M * 2048);    \
        __builtin_amdgcn_s_setprio(1);                                        \
        _Pragma("unroll")                                                     \
        for (int M = 0; M < 4; ++M)                                           \
            _Pragma("unroll")                                                 \
            for (int N = 0; N < 4; ++N)                                       \
                acc[M][N] = __builtin_amdgcn_mfma_scale_f32_16x16x128_f8f6f4( \
                    af[M], bfr[N], acc[M][N], 0, 0, 0, 0x7f7f7f7f, 0, 0x7f7f7f7f); \
        __builtin_amdgcn_s_setprio(0);                                        \
        _Pragma("unroll")                                                     \
        for (int M = 0; M < 4; ++M) LDFRAG(af[M], (Ab) + aoff + (M + 4) * 2048); \
        __builtin_amdgcn_s_setprio(1);                                        \
        _Pragma("unroll")                                                     \
        for (int M = 0; M < 4; ++M)                                           \
            _Pragma("unroll")                                                 \
            for (int N = 0; N < 4; ++N)                                       \
                acc[M + 4][N] = __builtin_amdgcn_mfma_scale_f32_16x16x128_f8f6f4( \
                    af[M], bfr[N], acc[M + 4][N], 0, 0, 0, 0x7f7f7f7f, 0, 0x7f7f7f7f); \
        __builtin_amdgcn_s_setprio(0); }

    // barrier + fences: vmcnt asm has "memory" clobber (orders STAGE before it);
    // empty asm fence + sched_barrier after s_barrier keep ds_reads below the
    // barrier (cross-wave staging visibility; rule #18/#21 discipline).
#define SYNCPT() {                                                            \
        asm volatile("s_waitcnt vmcnt(8)" ::: "memory");                      \
        __builtin_amdgcn_s_barrier();                                         \
        asm volatile("" ::: "memory");                                        \
        __builtin_amdgcn_sched_barrier(0); }

    STAGE(ldsA0, ldsB0, 0);
#pragma unroll 1
    for (int t = 0; t < NTKF; t += 2) {
        { const int k1 = (t + 1 < NTKF) ? t + 1 : NTKF - 1;   // clamp: uniform vmcnt
          STAGE(ldsA1, ldsB1, k1); }
        SYNCPT();
        COMPUTE(ldsA0, ldsB0);
        { const int k2 = (t + 2 < NTKF) ? t + 2 : NTKF - 1;   // dead re-stage at tail
          STAGE(ldsA0, ldsB0, k2); }
        SYNCPT();
        COMPUTE(ldsA1, ldsB1);
    }
#undef SYNCPT
#undef COMPUTE
#undef LDFRAG
#undef STAGE

    // ---- epilogue: score = G * invbn[col]; per-row best/worst (C/D: col=l&15, row=(l>>4)*4+i)
    float ib[4];
#pragma unroll
    for (int N = 0; N < 4; ++N) ib[N] = invbn[colbase + wc * 64 + N * 16 + frow];

#pragma unroll
    for (int M = 0; M < 8; ++M) {
#pragma unroll
        for (int i = 0; i < 4; ++i) {
            float bv = -3.4e38f, wv = 3.4e38f; int bi = 0x7fffffff, wi = 0x7fffffff;
#pragma unroll
            for (int N = 0; N < 4; ++N) {
                float sc = acc[M][N][i] * ib[N];
                int ci = colbase + wc * 64 + N * 16 + frow;
                if (sc > bv) { bv = sc; bi = ci; }
                if (sc < wv) { wv = sc; wi = ci; }
            }
#pragma unroll
            for (int d = 1; d < 16; d <<= 1) {   // reduce across 16 col lanes
                float obv = __shfl_xor(bv, d); int obi = __shfl_xor(bi, d);
                if (obv > bv || (obv == bv && obi < bi)) { bv = obv; bi = obi; }
                float owv = __shfl_xor(wv, d); int owi = __shfl_xor(wi, d);
                if (owv < wv || (owv == wv && owi < wi)) { wv = owv; wi = owi; }
            }
            if ((l & 15) == 0) {
                int rl = wr * 128 + M * 16 + (l >> 4) * 4 + i;
                if (bv > s_bv[wc][rl] || (bv == s_bv[wc][rl] && bi < s_bi[wc][rl])) { s_bv[wc][rl] = bv; s_bi[wc][rl] = bi; }
                if (wv < s_wv[wc][rl] || (wv == s_wv[wc][rl] && wi < s_wi[wc][rl])) { s_wv[wc][rl] = wv; s_wi[wc][rl] = wi; }
            }
        }
    }

    __syncthreads();
    if (tid < 256) {
        float bv = s_bv[0][tid]; int bi = s_bi[0][tid];
        float wv = s_wv[0][tid]; int wi = s_wi[0][tid];
#pragma unroll
        for (int c = 1; c < 4; ++c) {
            if (s_bv[c][tid] > bv || (s_bv[c][tid] == bv && s_bi[c][tid] < bi)) { bv = s_bv[c][tid]; bi = s_bi[c][tid]; }
            if (s_wv[c][tid] < wv || (s_wv[c][tid] == wv && s_wi[c][tid] < wi)) { wv = s_wv[c][tid]; wi = s_wi[c][tid]; }
        }
        const int sp = blockIdx.y;
        bestv [(size_t)sp * HW + rowbase + tid] = bv;
        besti [(size_t)sp * HW + rowbase + tid] = bi;
        worstv[(size_t)sp * HW + rowbase + tid] = wv;
        worsti[(size_t)sp * HW + rowbase + tid] = wi;
    }
}

// ---------------- final: reduce splits, gathered cosines (fp8 rows), loss ----------------
__global__ void k_final(const u8* __restrict__ CT, const u8* __restrict__ ST,
                        const float* __restrict__ inv6,
                        const float* __restrict__ bestv, const int* __restrict__ besti,
                        const float* __restrict__ worstv, const int* __restrict__ worsti,
                        float* __restrict__ out) {
    const int w = threadIdx.x >> 6, l = threadIdx.x & 63;
    const int r = blockIdx.x * 4 + w;

    float bv = -3.4e38f, wv = 3.4e38f; int bi = 0x7fffffff, wi = 0x7fffffff;
    if (l < NS) {
        bv = bestv [(size_t)l * HW + r]; bi = besti [(size_t)l * HW + r];
        wv = worstv[(size_t)l * HW + r]; wi = worsti[(size_t)l * HW + r];
    }
#pragma unroll
    for (int d = 1; d < 64; d <<= 1) {
        float obv = __shfl_xor(bv, d); int obi = __shfl_xor(bi, d);
        if (obv > bv || (obv == bv && obi < bi)) { bv = obv; bi = obi; }
        float owv = __shfl_xor(wv, d); int owi = __shfl_xor(wi, d);
        if (owv < wv || (owv == wv && owi < wi)) { wv = owv; wi = owi; }
    }
    const int zb = bi, zw = wi;

    const u8* ar = CT + (size_t)r * CJ;
    const u8* bb = ST + (size_t)zb * CJ;
    const u8* bw = ST + (size_t)zw * CJ;
    float db[3] = {0.f, 0.f, 0.f}, dw[3] = {0.f, 0.f, 0.f};
#pragma unroll
    for (int it = 0; it < 9; ++it) {
        const int c = it * 256 + l * 4;
        u32 va = *(const u32*)(ar + c);
        u32 vb = *(const u32*)(bb + c);
        u32 vw = *(const u32*)(bw + c);
        const int seg = it / 3;  // 0: feats, 1: depth, 2: edge (768 = 3*256)
#pragma unroll
        for (int q = 0; q < 4; ++q) {
            float a = e4m3f((va >> (8 * q)) & 0xff);
            float b = e4m3f((vb >> (8 * q)) & 0xff);
            float ww = e4m3f((vw >> (8 * q)) & 0xff);
            db[seg] = fmaf(a, b, db[seg]);
            dw[seg] = fmaf(a, ww, dw[seg]);
        }
    }
#pragma unroll
    for (int d = 1; d < 64; d <<= 1) {
#pragma unroll
        for (int s = 0; s < 3; ++s) {
            db[s] += __shfl_xor(db[s], d);
            dw[s] += __shfl_xor(dw[s], d);
        }
    }
    if (l == 0) {
        float c0 = db[0] * inv6[0 * HW + r] * inv6[1 * HW + zb];
        float c1 = db[1] * inv6[2 * HW + r] * inv6[3 * HW + zb];
        float c2 = db[2] * inv6[4 * HW + r] * inv6[5 * HW + zb];
        float d0 = dw[0] * inv6[0 * HW + r] * inv6[1 * HW + zw];
        float d1 = dw[1] * inv6[2 * HW + r] * inv6[3 * HW + zw];
        float d2 = dw[2] * inv6[4 * HW + r] * inv6[5 * HW + zw];
        float contrib = (6.0f - c0 - c1 - c2 + d0 + d1 + d2) * (1.0f / 9216.0f);
        atomicAdd(out, contrib);
    }
}

extern "C" void kernel_launch(void* const* d_in, const int* in_sizes, int n_in,
                              void* d_out, int out_size, void* d_ws, size_t ws_size,
                              hipStream_t stream) {
    const float* x  = (const float*)d_in[0];
    const float* s  = (const float*)d_in[1];
    const float* rd = (const float*)d_in[2];
    const float* sd = (const float*)d_in[3];
    const float* re = (const float*)d_in[4];
    const float* se = (const float*)d_in[5];

    char* ws = (char*)d_ws;
    const size_t SZ8 = (size_t)HW * CJ;              // 21,233,664 B each (fp8)
    u8*    CT8    = (u8*)ws;
    u8*    ST8    = (u8*)(ws + SZ8);
    float* sq6    = (float*)(ws + 2 * SZ8);          // 6*HW floats
    float* inv6   = sq6 + 6 * HW;                    // 6*HW floats
    float* invbnj = inv6 + 6 * HW;                   // HW floats
    float* bestv  = invbnj + HW;                     // NS*HW floats
    int*   besti  = (int*)(bestv + (size_t)NS * HW);
    float* worstv = (float*)(besti + (size_t)NS * HW);
    int*   worsti = (int*)(worstv + (size_t)NS * HW);
    const size_t NEED = 2 * SZ8 + (size_t)(13 + 4 * NS) * HW * 4;
    if (ws_size < NEED) return;  // ws too small: fail loudly (wrong output)

    hipMemsetAsync(d_out, 0, sizeof(float), stream);

    k_transpose8<<<dim3(HW / 32, CJ / 32), dim3(32, 8), 0, stream>>>(x, rd, re, CT8);
    k_transpose8<<<dim3(HW / 32, CJ / 32), dim3(32, 8), 0, stream>>>(s, sd, se, ST8);
    k_colsq<<<dim3(HW / 256, 6), 256, 0, stream>>>(x, s, rd, sd, re, se, sq6, inv6);
    k_joint<<<HW / 256, 256, 0, stream>>>(sq6, invbnj);
    k_gemm_arg<<<dim3(HW / 256, NS), 512, 0, stream>>>(CT8, ST8, invbnj, bestv, besti, worstv, worsti);
    k_final<<<HW / 4, 256, 0, stream>>>(CT8, ST8, inv6, bestv, besti, worstv, worsti, (float*)d_out);
}